// Round 7
// baseline (76.362 us; speedup 1.0000x reference)
//
#include <hip/hip_runtime.h>
#include <math.h>

typedef float f2 __attribute__((ext_vector_type(2)));

#define HH 32
#define WW 32
#define PAD 34          // padded scalar r plane
#define PADW 34         // padded width (f2 units) of shifted pair planes
#define MROWS 18        // main pair plane rows: 16 + 2 halo
#define SROWS 17        // shifted pair plane rows
#define CHQ 10
#define SBS 10
#define KITERS 40

// packed f32 fma, weight pair in %2, broadcast LOW half to both lanes
static __device__ __forceinline__ double pkfma_lo(double a, double w, double c) {
    double d;
    asm("v_pk_fma_f32 %0, %1, %2, %3 op_sel:[0,0,0] op_sel_hi:[1,0,1]"
        : "=v"(d) : "v"(a), "v"(w), "v"(c));
    return d;
}
static __device__ __forceinline__ double pkfma_hi(double a, double w, double c) {
    double d;
    asm("v_pk_fma_f32 %0, %1, %2, %3 op_sel:[0,1,0] op_sel_hi:[1,1,1]"
        : "=v"(d) : "v"(a), "v"(w), "v"(c));
    return d;
}
static __device__ __forceinline__ f2 vmax2(f2 a, f2 b) {
    f2 r; r.x = fmaxf(a.x, b.x); r.y = fmaxf(a.y, b.y); return r;
}

__global__ __launch_bounds__(1024) void vin_kernel(
    const float* __restrict__ X,     // (bs,2,32,32)
    const int*   __restrict__ S1,    // (bs,10)
    const int*   __restrict__ S2,    // (bs,10)
    const float* __restrict__ bias,  // (150)
    const float* __restrict__ w0,    // (150,2,3,3)
    const float* __restrict__ w1,    // (150)
    const float* __restrict__ w,     // (10,1,3,3)
    const float* __restrict__ wfb,   // (10,1,3,3)
    const float* __restrict__ wo,    // (8,10)
    float* __restrict__ out,
    int bs)
{
    // per-image LDS slices [img]
    __shared__ float r_lds[2][PAD * PAD];
    __shared__ f2    mplane[2][2][MROWS * PADW];  // [img][pp]
    __shared__ f2    splane[2][2][SROWS * PADW];  // [img][pp]
    __shared__ float weff[19];                    // image-independent
    __shared__ float wpart[152];

    const int tid = threadIdx.x;
    const int img = tid >> 9;        // 0 or 1
    const int t   = tid & 511;       // intra-image thread id
    const int bimg = blockIdx.x * 2 + img;

    // ---- zero LDS (halo rows/cols stay zero = SAME padding) ----
    for (int i = tid; i < 2 * PAD * PAD; i += 1024) (&r_lds[0][0])[i] = 0.f;
    {
        const f2 z = (f2)(0.f);
        for (int i = tid; i < 2 * 2 * MROWS * PADW; i += 1024) (&mplane[0][0][0])[i] = z;
        for (int i = tid; i < 2 * 2 * SROWS * PADW; i += 1024) (&splane[0][0][0])[i] = z;
    }

    // ---- collapse (w0,bias) x w1 into an effective 2ch 3x3 conv (once) ----
    if (tid < 152) {
        const int o = tid >> 3;
        const int p = tid & 7;
        float s = 0.f;
        if (o < 18) {
            for (int c = p; c < 150; c += 8) s += w1[c] * w0[c * 18 + o];
        } else {
            for (int c = p; c < 150; c += 8) s += w1[c] * bias[c];
        }
        wpart[tid] = s;
    }
    __syncthreads();
    if (tid < 19) {
        float s = 0.f;
        #pragma unroll
        for (int p = 0; p < 8; ++p) s += wpart[tid * 8 + p];
        weff[tid] = s;
    }
    __syncthreads();

    // ---- thread -> 2 vertically adjacent pixels of image `img` ----
    const int x  = t & 31;
    const int m  = t >> 5;           // pair row 0..15
    const int y0 = m * 2;
    const int cx = x + 1;
    const int sbase = m * PADW + cx;
    const int mbase = (m + 1) * PADW + cx;

    float we[19];
    #pragma unroll
    for (int i = 0; i < 19; ++i) we[i] = weff[i];

    // ---- r = conv(X, w_eff) + b_eff ----
    const float* Xb = X + (size_t)bimg * 2 * HH * WW;
    #pragma unroll
    for (int dy = 0; dy < 2; ++dy) {
        const int y = y0 + dy;
        float acc = we[18];
        #pragma unroll
        for (int ci = 0; ci < 2; ++ci)
        #pragma unroll
        for (int ky = 0; ky < 3; ++ky)
        #pragma unroll
        for (int kx = 0; kx < 3; ++kx) {
            const int yy = y + ky - 1, xx = x + kx - 1;
            const float xv = (yy >= 0 && yy < HH && xx >= 0 && xx < WW)
                           ? Xb[ci * (HH * WW) + yy * WW + xx] : 0.f;
            acc += we[ci * 9 + ky * 3 + kx] * xv;
        }
        r_lds[img][(y + 1) * PAD + cx] = acc;
    }
    __syncthreads();

    // ---- qr = conv(r, w) per pixel (loop-invariant), v0 = max_oc qr ----
    float wr[CHQ][9];
    #pragma unroll
    for (int oc = 0; oc < CHQ; ++oc)
    #pragma unroll
    for (int k = 0; k < 9; ++k) wr[oc][k] = w[oc * 9 + k];

    float nb[4][3];
    #pragma unroll
    for (int rr = 0; rr < 4; ++rr)
    #pragma unroll
    for (int cc = 0; cc < 3; ++cc) nb[rr][cc] = r_lds[img][(y0 + rr) * PAD + (x + cc)];

    double qrd[CHQ];
    f2 v02;
    {
        float v0a = -1e30f, v0b = -1e30f;
        #pragma unroll
        for (int oc = 0; oc < CHQ; ++oc) {
            float t0 = 0.f, t1 = 0.f;
            #pragma unroll
            for (int ky = 0; ky < 3; ++ky)
            #pragma unroll
            for (int kx = 0; kx < 3; ++kx) {
                t0 += wr[oc][ky * 3 + kx] * nb[0 + ky][kx];
                t1 += wr[oc][ky * 3 + kx] * nb[1 + ky][kx];
            }
            f2 q; q.x = t0; q.y = t1;
            qrd[oc] = __builtin_bit_cast(double, q);
            v0a = fmaxf(v0a, t0); v0b = fmaxf(v0b, t1);
        }
        v02.x = v0a; v02.y = v0b;
    }
    mplane[img][0][mbase] = v02;
    splane[img][0][sbase].y = v02.x;
    splane[img][0][sbase + PADW].x = v02.y;
    __syncthreads();

    // ---- packed w_fb pairs ----
    double WF[45];
    #pragma unroll
    for (int p = 0; p < 45; ++p) WF[p] = ((const double*)wfb)[p];

    // ---- one VI step: v <- max_oc(qr + conv(v, w_fb)) ----
#define VI_STEP(CUR, NXT) do {                                                      \
        double da[9];                                                               \
        _Pragma("unroll")                                                           \
        for (int c = 0; c < 3; ++c) {                                               \
            da[0 + c] = __builtin_bit_cast(double, splane[img][CUR][sbase + c - 1]);        \
            da[3 + c] = __builtin_bit_cast(double, mplane[img][CUR][mbase + c - 1]);        \
            da[6 + c] = __builtin_bit_cast(double, splane[img][CUR][sbase + PADW + c - 1]); \
        }                                                                           \
        f2 vm;                                                                      \
        _Pragma("unroll")                                                           \
        for (int oc = 0; oc < CHQ; ++oc) {                                          \
            double tt = qrd[oc];                                                    \
            _Pragma("unroll")                                                       \
            for (int j = 0; j < 9; ++j) {                                           \
                const int k = oc * 9 + j;                                           \
                if ((k & 1) == 0) tt = pkfma_lo(da[j], WF[k >> 1], tt);             \
                else              tt = pkfma_hi(da[j], WF[k >> 1], tt);             \
            }                                                                       \
            const f2 tv = __builtin_bit_cast(f2, tt);                               \
            vm = (oc == 0) ? tv : vmax2(vm, tv);                                    \
        }                                                                           \
        mplane[img][NXT][mbase] = vm;                                               \
        splane[img][NXT][sbase].y = vm.x;                                           \
        splane[img][NXT][sbase + PADW].x = vm.y;                                    \
        __syncthreads();                                                            \
    } while (0)

    // 39 steps: 19 x (0->1, 1->0) + final 0->1; result in buffers[1]
    #pragma unroll 1
    for (int itp = 0; itp < 19; ++itp) {
        VI_STEP(0, 1);
        VI_STEP(1, 0);
    }
    VI_STEP(0, 1);

    // ---- final q at the 10 gather points; 10->8 matmul + softmax ----
    if (t < SBS) {
        const f2* vfin = &mplane[img][1][0];
        const int row = bimg * SBS + t;
        const int s1 = S1[row];
        const int s2 = S2[row];

        float fq[CHQ];
        #pragma unroll
        for (int oc = 0; oc < CHQ; ++oc) {
            float tt = 0.f;
            #pragma unroll
            for (int ky = 0; ky < 3; ++ky)
            #pragma unroll
            for (int kx = 0; kx < 3; ++kx) {
                const int yy = s1 + ky - 1;        // -1..32
                const int xx = s2 + kx - 1;        // -1..32
                const int pry = 1 + (yy >> 1);     // arithmetic shift: -1 -> 0
                const float vv = vfin[pry * PADW + (xx + 1)][yy & 1];
                tt += w[oc * 9 + ky * 3 + kx]   * r_lds[img][(yy + 1) * PAD + (xx + 1)]
                    + wfb[oc * 9 + ky * 3 + kx] * vv;
            }
            fq[oc] = tt;
        }

        float o8[8];
        float mx = -1e30f;
        #pragma unroll
        for (int o = 0; o < 8; ++o) {
            float tt = 0.f;
            #pragma unroll
            for (int oc = 0; oc < CHQ; ++oc) tt += fq[oc] * wo[o * 10 + oc];
            o8[o] = tt;
            mx = fmaxf(mx, tt);
        }
        float e[8];
        float es = 0.f;
        #pragma unroll
        for (int o = 0; o < 8; ++o) { e[o] = expf(o8[o] - mx); es += e[o]; }
        const float inv = 1.f / es;

        #pragma unroll
        for (int o = 0; o < 8; ++o) {
            out[(size_t)row * 8 + o] = o8[o];
            out[(size_t)bs * SBS * 8 + (size_t)row * 8 + o] = e[o] * inv;
        }
    }
}

extern "C" void kernel_launch(void* const* d_in, const int* in_sizes, int n_in,
                              void* d_out, int out_size, void* d_ws, size_t ws_size,
                              hipStream_t stream) {
    const float* X    = (const float*)d_in[0];
    const int*   S1   = (const int*)d_in[1];
    const int*   S2   = (const int*)d_in[2];
    const float* bias = (const float*)d_in[3];
    const float* w0   = (const float*)d_in[4];
    const float* w1   = (const float*)d_in[5];
    const float* w    = (const float*)d_in[6];
    const float* wfb  = (const float*)d_in[7];
    const float* wo   = (const float*)d_in[8];
    float* out        = (float*)d_out;

    const int bs = in_sizes[0] / (2 * HH * WW);   // 256

    vin_kernel<<<bs / 2, 1024, 0, stream>>>(X, S1, S2, bias, w0, w1, w, wfb, wo, out, bs);
}

// Round 8
// 50.793 us; speedup vs baseline: 1.5034x; 1.5034x over previous
//
#include <hip/hip_runtime.h>
#include <math.h>

typedef float f2 __attribute__((ext_vector_type(2)));

#define HH 32
#define WW 32
#define PAD 34          // padded scalar r plane
#define PADW 34         // padded width (f2 units) of shifted pair planes
#define MROWS 18        // main pair plane rows: 16 + 2 halo
#define SROWS 17        // shifted pair plane rows
#define CHQ 10
#define SBS 10
#define KITERS 40

// packed f32 fma; weight pair in an SGPR pair (uniform), broadcast LOW half
static __device__ __forceinline__ double pkfma_lo(double a, double w, double c) {
    double d;
    asm("v_pk_fma_f32 %0, %1, %2, %3 op_sel:[0,0,0] op_sel_hi:[1,0,1]"
        : "=v"(d) : "v"(a), "s"(w), "v"(c));
    return d;
}
// broadcast HIGH half of the SGPR weight pair
static __device__ __forceinline__ double pkfma_hi(double a, double w, double c) {
    double d;
    asm("v_pk_fma_f32 %0, %1, %2, %3 op_sel:[0,1,0] op_sel_hi:[1,1,1]"
        : "=v"(d) : "v"(a), "s"(w), "v"(c));
    return d;
}
static __device__ __forceinline__ f2 vmax2(f2 a, f2 b) {
    f2 r; r.x = fmaxf(a.x, b.x); r.y = fmaxf(a.y, b.y); return r;
}

__global__ __launch_bounds__(1024) void vin_kernel(
    const float* __restrict__ X,     // (bs,2,32,32)
    const int*   __restrict__ S1,    // (bs,10)
    const int*   __restrict__ S2,    // (bs,10)
    const float* __restrict__ bias,  // (150)
    const float* __restrict__ w0,    // (150,2,3,3)
    const float* __restrict__ w1,    // (150)
    const float* __restrict__ w,     // (10,1,3,3)
    const float* __restrict__ wfb,   // (10,1,3,3)
    const float* __restrict__ wo,    // (8,10)
    float* __restrict__ out,
    int bs)
{
    // per-image LDS slices [img]
    __shared__ float r_lds[2][PAD * PAD];
    __shared__ f2    mplane[2][2][MROWS * PADW];  // [img][pp]
    __shared__ f2    splane[2][2][SROWS * PADW];  // [img][pp]
    __shared__ float weff[19];                    // image-independent
    __shared__ float wpart[152];

    const int tid = threadIdx.x;
    const int img = tid >> 9;        // 0 or 1
    const int t   = tid & 511;       // intra-image thread id
    const int bimg = blockIdx.x * 2 + img;

    // ---- zero LDS (halo rows/cols stay zero = SAME padding) ----
    for (int i = tid; i < 2 * PAD * PAD; i += 1024) (&r_lds[0][0])[i] = 0.f;
    {
        const f2 z = (f2)(0.f);
        for (int i = tid; i < 2 * 2 * MROWS * PADW; i += 1024) (&mplane[0][0][0])[i] = z;
        for (int i = tid; i < 2 * 2 * SROWS * PADW; i += 1024) (&splane[0][0][0])[i] = z;
    }

    // ---- collapse (w0,bias) x w1 into an effective 2ch 3x3 conv (once) ----
    if (tid < 152) {
        const int o = tid >> 3;
        const int p = tid & 7;
        float s = 0.f;
        if (o < 18) {
            for (int c = p; c < 150; c += 8) s += w1[c] * w0[c * 18 + o];
        } else {
            for (int c = p; c < 150; c += 8) s += w1[c] * bias[c];
        }
        wpart[tid] = s;
    }
    __syncthreads();
    if (tid < 19) {
        float s = 0.f;
        #pragma unroll
        for (int p = 0; p < 8; ++p) s += wpart[tid * 8 + p];
        weff[tid] = s;
    }
    __syncthreads();

    // ---- thread -> 2 vertically adjacent pixels of image `img` ----
    const int x  = t & 31;
    const int m  = t >> 5;           // pair row 0..15
    const int y0 = m * 2;
    const int cx = x + 1;
    const int sbase = m * PADW + cx;
    const int mbase = (m + 1) * PADW + cx;

    float we[19];
    #pragma unroll
    for (int i = 0; i < 19; ++i) we[i] = weff[i];

    // ---- r = conv(X, w_eff) + b_eff ----
    const float* Xb = X + (size_t)bimg * 2 * HH * WW;
    #pragma unroll
    for (int dy = 0; dy < 2; ++dy) {
        const int y = y0 + dy;
        float acc = we[18];
        #pragma unroll
        for (int ci = 0; ci < 2; ++ci)
        #pragma unroll
        for (int ky = 0; ky < 3; ++ky)
        #pragma unroll
        for (int kx = 0; kx < 3; ++kx) {
            const int yy = y + ky - 1, xx = x + kx - 1;
            const float xv = (yy >= 0 && yy < HH && xx >= 0 && xx < WW)
                           ? Xb[ci * (HH * WW) + yy * WW + xx] : 0.f;
            acc += we[ci * 9 + ky * 3 + kx] * xv;
        }
        r_lds[img][(y + 1) * PAD + cx] = acc;
    }
    __syncthreads();

    // ---- qr = conv(r, w) per pixel (loop-invariant), v0 = max_oc qr ----
    float nb[4][3];
    #pragma unroll
    for (int rr = 0; rr < 4; ++rr)
    #pragma unroll
    for (int cc = 0; cc < 3; ++cc) nb[rr][cc] = r_lds[img][(y0 + rr) * PAD + (x + cc)];

    double qrd[CHQ];
    f2 v02;
    {
        float v0a = -1e30f, v0b = -1e30f;
        #pragma unroll
        for (int oc = 0; oc < CHQ; ++oc) {
            float t0 = 0.f, t1 = 0.f;
            #pragma unroll
            for (int ky = 0; ky < 3; ++ky)
            #pragma unroll
            for (int kx = 0; kx < 3; ++kx) {
                const float wv = w[oc * 9 + ky * 3 + kx];
                t0 += wv * nb[0 + ky][kx];
                t1 += wv * nb[1 + ky][kx];
            }
            f2 q; q.x = t0; q.y = t1;
            qrd[oc] = __builtin_bit_cast(double, q);
            v0a = fmaxf(v0a, t0); v0b = fmaxf(v0b, t1);
        }
        v02.x = v0a; v02.y = v0b;
    }
    mplane[img][0][mbase] = v02;
    splane[img][0][sbase].y = v02.x;
    splane[img][0][sbase + PADW].x = v02.y;
    __syncthreads();

    // ---- packed w_fb pairs (uniform -> SGPR pairs) ----
    double WF[45];
    #pragma unroll
    for (int p = 0; p < 45; ++p) WF[p] = ((const double*)wfb)[p];

    // ---- one VI step: v <- max_oc(qr + conv(v, w_fb)) ----
#define VI_STEP(CUR, NXT) do {                                                      \
        double da[9];                                                               \
        _Pragma("unroll")                                                           \
        for (int c = 0; c < 3; ++c) {                                               \
            da[0 + c] = __builtin_bit_cast(double, splane[img][CUR][sbase + c - 1]);        \
            da[3 + c] = __builtin_bit_cast(double, mplane[img][CUR][mbase + c - 1]);        \
            da[6 + c] = __builtin_bit_cast(double, splane[img][CUR][sbase + PADW + c - 1]); \
        }                                                                           \
        f2 vm;                                                                      \
        _Pragma("unroll")                                                           \
        for (int oc = 0; oc < CHQ; ++oc) {                                          \
            double tt = qrd[oc];                                                    \
            _Pragma("unroll")                                                       \
            for (int j = 0; j < 9; ++j) {                                           \
                const int k = oc * 9 + j;                                           \
                if ((k & 1) == 0) tt = pkfma_lo(da[j], WF[k >> 1], tt);             \
                else              tt = pkfma_hi(da[j], WF[k >> 1], tt);             \
            }                                                                       \
            const f2 tv = __builtin_bit_cast(f2, tt);                               \
            vm = (oc == 0) ? tv : vmax2(vm, tv);                                    \
        }                                                                           \
        mplane[img][NXT][mbase] = vm;                                               \
        splane[img][NXT][sbase].y = vm.x;                                           \
        splane[img][NXT][sbase + PADW].x = vm.y;                                    \
        __syncthreads();                                                            \
    } while (0)

    // 39 steps: 19 x (0->1, 1->0) + final 0->1; result in buffers[1]
    #pragma unroll 1
    for (int itp = 0; itp < 19; ++itp) {
        VI_STEP(0, 1);
        VI_STEP(1, 0);
    }
    VI_STEP(0, 1);

    // ---- final q at the 10 gather points; 10->8 matmul + softmax ----
    if (t < SBS) {
        const f2* vfin = &mplane[img][1][0];
        const int row = bimg * SBS + t;
        const int s1 = S1[row];
        const int s2 = S2[row];

        float fq[CHQ];
        #pragma unroll
        for (int oc = 0; oc < CHQ; ++oc) {
            float tt = 0.f;
            #pragma unroll
            for (int ky = 0; ky < 3; ++ky)
            #pragma unroll
            for (int kx = 0; kx < 3; ++kx) {
                const int yy = s1 + ky - 1;        // -1..32
                const int xx = s2 + kx - 1;        // -1..32
                const int pry = 1 + (yy >> 1);     // arithmetic shift: -1 -> 0
                const float vv = vfin[pry * PADW + (xx + 1)][yy & 1];
                tt += w[oc * 9 + ky * 3 + kx]   * r_lds[img][(yy + 1) * PAD + (xx + 1)]
                    + wfb[oc * 9 + ky * 3 + kx] * vv;
            }
            fq[oc] = tt;
        }

        float o8[8];
        float mx = -1e30f;
        #pragma unroll
        for (int o = 0; o < 8; ++o) {
            float tt = 0.f;
            #pragma unroll
            for (int oc = 0; oc < CHQ; ++oc) tt += fq[oc] * wo[o * 10 + oc];
            o8[o] = tt;
            mx = fmaxf(mx, tt);
        }
        float e[8];
        float es = 0.f;
        #pragma unroll
        for (int o = 0; o < 8; ++o) { e[o] = expf(o8[o] - mx); es += e[o]; }
        const float inv = 1.f / es;

        #pragma unroll
        for (int o = 0; o < 8; ++o) {
            out[(size_t)row * 8 + o] = o8[o];
            out[(size_t)bs * SBS * 8 + (size_t)row * 8 + o] = e[o] * inv;
        }
    }
}

extern "C" void kernel_launch(void* const* d_in, const int* in_sizes, int n_in,
                              void* d_out, int out_size, void* d_ws, size_t ws_size,
                              hipStream_t stream) {
    const float* X    = (const float*)d_in[0];
    const int*   S1   = (const int*)d_in[1];
    const int*   S2   = (const int*)d_in[2];
    const float* bias = (const float*)d_in[3];
    const float* w0   = (const float*)d_in[4];
    const float* w1   = (const float*)d_in[5];
    const float* w    = (const float*)d_in[6];
    const float* wfb  = (const float*)d_in[7];
    const float* wo   = (const float*)d_in[8];
    float* out        = (float*)d_out;

    const int bs = in_sizes[0] / (2 * HH * WW);   // 256

    vin_kernel<<<bs / 2, 1024, 0, stream>>>(X, S1, S2, bias, w0, w1, w, wfb, wo, out, bs);
}

// Round 9
// 35.484 us; speedup vs baseline: 2.1520x; 1.4314x over previous
//
#include <hip/hip_runtime.h>
#include <math.h>

typedef float f2 __attribute__((ext_vector_type(2)));

#define HH 32
#define WW 32
#define PAD 34          // padded scalar r plane
#define PADW 34         // padded width (f2 units) of shifted pair planes
#define MROWS 18        // main pair plane rows: 16 + 2 halo
#define SROWS 17        // shifted pair plane rows
#define CHQ 10
#define SBS 10
#define KITERS 40

// packed f32 fma; weight pair lives in an SGPR pair (uniform), broadcast LOW half
static __device__ __forceinline__ double pkfma_lo(double a, double w, double c) {
    double d;
    asm("v_pk_fma_f32 %0, %1, %2, %3 op_sel:[0,0,0] op_sel_hi:[1,0,1]"
        : "=v"(d) : "v"(a), "s"(w), "v"(c));
    return d;
}
// broadcast HIGH half of the SGPR weight pair
static __device__ __forceinline__ double pkfma_hi(double a, double w, double c) {
    double d;
    asm("v_pk_fma_f32 %0, %1, %2, %3 op_sel:[0,1,0] op_sel_hi:[1,1,1]"
        : "=v"(d) : "v"(a), "s"(w), "v"(c));
    return d;
}

__global__ __launch_bounds__(512) void vin_kernel(
    const float* __restrict__ X,     // (bs,2,32,32)
    const int*   __restrict__ S1,    // (bs,10)
    const int*   __restrict__ S2,    // (bs,10)
    const float* __restrict__ bias,  // (150)
    const float* __restrict__ w0,    // (150,2,3,3)
    const float* __restrict__ w1,    // (150)
    const float* __restrict__ w,     // (10,1,3,3)
    const float* __restrict__ wfb,   // (10,1,3,3)
    const float* __restrict__ wo,    // (8,10)
    float* __restrict__ out,
    int bs)
{
    __shared__ float r_lds[PAD * PAD];
    __shared__ f2    mplane[2][MROWS * PADW];
    __shared__ f2    splane[2][SROWS * PADW];
    __shared__ float weff[19];
    __shared__ float wpart[152];

    const int tid = threadIdx.x;
    const int b   = blockIdx.x;

    // ---- zero LDS (halo rows/cols stay zero = SAME padding) ----
    for (int i = tid; i < PAD * PAD; i += 512) r_lds[i] = 0.f;
    {
        const f2 z = (f2)(0.f);
        for (int i = tid; i < 2 * MROWS * PADW; i += 512) (&mplane[0][0])[i] = z;
        for (int i = tid; i < 2 * SROWS * PADW; i += 512) (&splane[0][0])[i] = z;
    }

    // ---- collapse (w0,bias) x w1 into an effective 2ch 3x3 conv ----
    if (tid < 152) {
        const int o = tid >> 3;
        const int p = tid & 7;
        float s = 0.f;
        if (o < 18) {
            for (int c = p; c < 150; c += 8) s += w1[c] * w0[c * 18 + o];
        } else {
            for (int c = p; c < 150; c += 8) s += w1[c] * bias[c];
        }
        wpart[tid] = s;
    }
    __syncthreads();
    if (tid < 19) {
        float s = 0.f;
        #pragma unroll
        for (int p = 0; p < 8; ++p) s += wpart[tid * 8 + p];
        weff[tid] = s;
    }
    __syncthreads();

    // ---- thread -> 2 vertically adjacent pixels ----
    const int x  = tid & 31;
    const int m  = tid >> 5;         // pair row 0..15
    const int y0 = m * 2;
    const int cx = x + 1;
    const int sbase = m * PADW + cx;
    const int mbase = (m + 1) * PADW + cx;

    float we[19];
    #pragma unroll
    for (int i = 0; i < 19; ++i) we[i] = weff[i];

    // ---- r = conv(X, w_eff) + b_eff ----
    const float* Xb = X + (size_t)b * 2 * HH * WW;
    #pragma unroll
    for (int dy = 0; dy < 2; ++dy) {
        const int y = y0 + dy;
        float acc = we[18];
        #pragma unroll
        for (int ci = 0; ci < 2; ++ci)
        #pragma unroll
        for (int ky = 0; ky < 3; ++ky)
        #pragma unroll
        for (int kx = 0; kx < 3; ++kx) {
            const int yy = y + ky - 1, xx = x + kx - 1;
            const float xv = (yy >= 0 && yy < HH && xx >= 0 && xx < WW)
                           ? Xb[ci * (HH * WW) + yy * WW + xx] : 0.f;
            acc += we[ci * 9 + ky * 3 + kx] * xv;
        }
        r_lds[(y + 1) * PAD + cx] = acc;
    }
    __syncthreads();

    // ---- qr = conv(r, w) per pixel (loop-invariant), v0 = max_oc qr ----
    float nb[4][3];
    #pragma unroll
    for (int rr = 0; rr < 4; ++rr)
    #pragma unroll
    for (int cc = 0; cc < 3; ++cc) nb[rr][cc] = r_lds[(y0 + rr) * PAD + (x + cc)];

    double qrd[CHQ];
    f2 v02;
    {
        float v0a = -1e30f, v0b = -1e30f;
        #pragma unroll
        for (int oc = 0; oc < CHQ; ++oc) {
            float t0 = 0.f, t1 = 0.f;
            #pragma unroll
            for (int ky = 0; ky < 3; ++ky)
            #pragma unroll
            for (int kx = 0; kx < 3; ++kx) {
                const float wv = w[oc * 9 + ky * 3 + kx];
                t0 += wv * nb[0 + ky][kx];
                t1 += wv * nb[1 + ky][kx];
            }
            f2 q; q.x = t0; q.y = t1;
            qrd[oc] = __builtin_bit_cast(double, q);
            v0a = fmaxf(v0a, t0); v0b = fmaxf(v0b, t1);
        }
        v02.x = v0a; v02.y = v0b;
    }
    mplane[0][mbase] = v02;
    splane[0][sbase].y = v02.x;
    splane[0][sbase + PADW].x = v02.y;
    __syncthreads();

    // ---- packed w_fb pairs (uniform -> SGPR pairs) ----
    double WF[45];
    #pragma unroll
    for (int p = 0; p < 45; ++p) WF[p] = ((const double*)wfb)[p];

    // ---- one VI step: v <- max_oc(qr + conv(v, w_fb)) ----
#define VI_STEP(CUR, NXT) do {                                                      \
        double da[9];                                                               \
        _Pragma("unroll")                                                           \
        for (int c = 0; c < 3; ++c) {                                               \
            da[0 + c] = __builtin_bit_cast(double, splane[CUR][sbase + c - 1]);     \
            da[3 + c] = __builtin_bit_cast(double, mplane[CUR][mbase + c - 1]);     \
            da[6 + c] = __builtin_bit_cast(double, splane[CUR][sbase + PADW + c - 1]); \
        }                                                                           \
        f2 tv[CHQ];                                                                 \
        _Pragma("unroll")                                                           \
        for (int oc = 0; oc < CHQ; ++oc) {                                          \
            double tt = qrd[oc];                                                    \
            _Pragma("unroll")                                                       \
            for (int j = 0; j < 9; ++j) {                                           \
                const int k = oc * 9 + j;                                           \
                if ((k & 1) == 0) tt = pkfma_lo(da[j], WF[k >> 1], tt);             \
                else              tt = pkfma_hi(da[j], WF[k >> 1], tt);             \
            }                                                                       \
            tv[oc] = __builtin_bit_cast(f2, tt);                                    \
        }                                                                           \
        f2 vm;                                                                      \
        /* max3-friendly reduction per component */                                 \
        vm.x = fmaxf(fmaxf(fmaxf(tv[0].x, tv[1].x), tv[2].x),                       \
                     fmaxf(fmaxf(tv[3].x, tv[4].x),                                 \
                           fmaxf(fmaxf(tv[5].x, tv[6].x),                           \
                                 fmaxf(fmaxf(tv[7].x, tv[8].x), tv[9].x))));        \
        vm.y = fmaxf(fmaxf(fmaxf(tv[0].y, tv[1].y), tv[2].y),                       \
                     fmaxf(fmaxf(tv[3].y, tv[4].y),                                 \
                           fmaxf(fmaxf(tv[5].y, tv[6].y),                           \
                                 fmaxf(fmaxf(tv[7].y, tv[8].y), tv[9].y))));        \
        mplane[NXT][mbase] = vm;                                                    \
        splane[NXT][sbase].y = vm.x;                                                \
        splane[NXT][sbase + PADW].x = vm.y;                                         \
        __syncthreads();                                                            \
    } while (0)

    // 39 steps: 19 x (0->1, 1->0) + final 0->1; result in buffers[1]
    #pragma unroll 1
    for (int itp = 0; itp < 19; ++itp) {
        VI_STEP(0, 1);
        VI_STEP(1, 0);
    }
    VI_STEP(0, 1);

    // ---- final q at the 10 gather points; 10->8 matmul + softmax ----
    if (tid < SBS) {
        const f2* vfin = &mplane[1][0];
        const int row = b * SBS + tid;
        const int s1 = S1[row];
        const int s2 = S2[row];

        float fq[CHQ];
        #pragma unroll
        for (int oc = 0; oc < CHQ; ++oc) {
            float tt = 0.f;
            #pragma unroll
            for (int ky = 0; ky < 3; ++ky)
            #pragma unroll
            for (int kx = 0; kx < 3; ++kx) {
                const int yy = s1 + ky - 1;        // -1..32
                const int xx = s2 + kx - 1;        // -1..32
                const int pry = 1 + (yy >> 1);     // arithmetic shift: -1 -> 0
                const float vv = vfin[pry * PADW + (xx + 1)][yy & 1];
                tt += w[oc * 9 + ky * 3 + kx]   * r_lds[(yy + 1) * PAD + (xx + 1)]
                    + wfb[oc * 9 + ky * 3 + kx] * vv;
            }
            fq[oc] = tt;
        }

        float o8[8];
        float mx = -1e30f;
        #pragma unroll
        for (int o = 0; o < 8; ++o) {
            float tt = 0.f;
            #pragma unroll
            for (int oc = 0; oc < CHQ; ++oc) tt += fq[oc] * wo[o * 10 + oc];
            o8[o] = tt;
            mx = fmaxf(mx, tt);
        }
        float e[8];
        float es = 0.f;
        #pragma unroll
        for (int o = 0; o < 8; ++o) { e[o] = expf(o8[o] - mx); es += e[o]; }
        const float inv = 1.f / es;

        #pragma unroll
        for (int o = 0; o < 8; ++o) {
            out[(size_t)row * 8 + o] = o8[o];
            out[(size_t)bs * SBS * 8 + (size_t)row * 8 + o] = e[o] * inv;
        }
    }
}

extern "C" void kernel_launch(void* const* d_in, const int* in_sizes, int n_in,
                              void* d_out, int out_size, void* d_ws, size_t ws_size,
                              hipStream_t stream) {
    const float* X    = (const float*)d_in[0];
    const int*   S1   = (const int*)d_in[1];
    const int*   S2   = (const int*)d_in[2];
    const float* bias = (const float*)d_in[3];
    const float* w0   = (const float*)d_in[4];
    const float* w1   = (const float*)d_in[5];
    const float* w    = (const float*)d_in[6];
    const float* wfb  = (const float*)d_in[7];
    const float* wo   = (const float*)d_in[8];
    float* out        = (float*)d_out;

    const int bs = in_sizes[0] / (2 * HH * WW);   // 256

    vin_kernel<<<bs, 512, 0, stream>>>(X, S1, S2, bias, w0, w1, w, wfb, wo, out, bs);
}